// Round 10
// baseline (396.599 us; speedup 1.0000x reference)
//
#include <hip/hip_runtime.h>

#define D 64

// ---------------------------------------------------------------------------
// edge_index dtype detection (int32 vs int64), done per-block on device.
// int64 little-endian with values < 2^32 => every odd uint32 word is 0.
// int32 random indices in [0,100000): P(64 odd words all zero) ~ 1e-320.
// ---------------------------------------------------------------------------
#define DETECT_IS64(ei)                                        \
  __shared__ int s_is64;                                       \
  if (threadIdx.x == 0) {                                      \
    const unsigned int* w_ = (const unsigned int*)(ei);        \
    int is64_ = 1;                                             \
    for (int i_ = 0; i_ < 64; ++i_) {                          \
      if (w_[2 * i_ + 1] != 0u) { is64_ = 0; break; }          \
    }                                                          \
    s_is64 = is64_;                                            \
  }                                                            \
  __syncthreads();

// Grid/block for hist & place MUST be identical: shard = blockIdx & (S-1)
// must map each edge to the same shard in both kernels.
#define EDGE_GRID 4096
#define EDGE_BLOCK 256

// Scan parallelism: 8192 chunks (round-5 lesson: 1024 x 782 serial iters
// was 335 us at 0.18% occupancy; 8192 x ~98 restores latency hiding).
#define SCAN_CHUNKS 8192

// ---------------------------------------------------------------------------
// Kernel 1: sharded histogram. key = shard*N + dst, shard = blockIdx&(S-1).
// Cursor lines for shard s are only touched by blocks with blockIdx%S == s
// -> (with round-robin block->XCD dispatch) atomics stay XCD-local in L2.
// ---------------------------------------------------------------------------
__global__ __launch_bounds__(256) void gin_hist_sharded(
    const void* __restrict__ edge_index, int* __restrict__ C,
    int n_edges, int n_nodes, int nshard) {
  DETECT_IS64(edge_index);
  const int* ei32 = (const int*)edge_index;
  const long long* ei64 = (const long long*)edge_index;
  int* Cs = C + (size_t)(blockIdx.x & (nshard - 1)) * n_nodes;
  const int i = (int)(blockIdx.x * blockDim.x + threadIdx.x);
  const int stride = (int)(gridDim.x * blockDim.x);
  for (int e = i; e < n_edges; e += stride) {
    const int dst = s_is64 ? (int)ei64[n_edges + e] : ei32[n_edges + e];
    atomicAdd(&Cs[dst], 1);
  }
}

// ---------------------------------------------------------------------------
// Kernels 2a/2b/2c: in-place exclusive scan of C[total], SCAN_CHUNKS chunks.
// ---------------------------------------------------------------------------
__global__ __launch_bounds__(256) void gin_scan_a(
    const int* __restrict__ C, int* __restrict__ tsum, int total, int chunk) {
  const int t = (int)(blockIdx.x * blockDim.x + threadIdx.x);
  if (t >= SCAN_CHUNKS) return;
  const int beg = t * chunk;
  const int end = min(beg + chunk, total);
  int s = 0;
  for (int i = beg; i < end; ++i) s += C[i];
  tsum[t] = s;
}

// One block, 1024 threads; each thread owns 8 contiguous partials.
__global__ __launch_bounds__(1024) void gin_scan_b(int* __restrict__ tsum) {
  __shared__ int ls[1024];
  const int t = threadIdx.x;
  int v[8];
  int s = 0;
#pragma unroll
  for (int i = 0; i < 8; ++i) {
    v[i] = tsum[t * 8 + i];
    s += v[i];
  }
  ls[t] = s;
  __syncthreads();
  for (int o = 1; o < 1024; o <<= 1) {
    const int a = (t >= o) ? ls[t - o] : 0;
    __syncthreads();
    ls[t] += a;
    __syncthreads();
  }
  int run = ls[t] - s;  // exclusive over this thread's 8
#pragma unroll
  for (int i = 0; i < 8; ++i) {
    tsum[t * 8 + i] = run;
    run += v[i];
  }
}

__global__ __launch_bounds__(256) void gin_scan_c(
    int* __restrict__ C, const int* __restrict__ tsum, int total, int chunk) {
  const int t = (int)(blockIdx.x * blockDim.x + threadIdx.x);
  if (t >= SCAN_CHUNKS) return;
  const int beg = t * chunk;
  const int end = min(beg + chunk, total);
  int run = tsum[t];
  for (int i = beg; i < end; ++i) {
    const int c = C[i];
    C[i] = run;
    run += c;
  }
}

// ---------------------------------------------------------------------------
// Kernel 3: sharded placement. pos = atomicAdd(&C[shard*N+dst], 1).
// After this kernel, C[k] = exclusive_prefix[k+1], so the segment for key k
// is [C[k-1] (or 0 for k==0), C[k]). Shard regions of `sorted` are written
// by a single XCD -> L2 merges the 4B appends.
// ---------------------------------------------------------------------------
__global__ __launch_bounds__(256) void gin_place_sharded(
    const void* __restrict__ edge_index, int* __restrict__ C,
    int* __restrict__ sorted_src, int n_edges, int n_nodes, int nshard) {
  DETECT_IS64(edge_index);
  const int* ei32 = (const int*)edge_index;
  const long long* ei64 = (const long long*)edge_index;
  int* Cs = C + (size_t)(blockIdx.x & (nshard - 1)) * n_nodes;
  const int i = (int)(blockIdx.x * blockDim.x + threadIdx.x);
  const int stride = (int)(gridDim.x * blockDim.x);
  for (int e = i; e < n_edges; e += stride) {
    int src, dst;
    if (s_is64) {
      src = (int)ei64[e];
      dst = (int)ei64[n_edges + e];
    } else {
      src = ei32[e];
      dst = ei32[n_edges + e];
    }
    const int pos = atomicAdd(&Cs[dst], 1);
    sorted_src[pos] = src;
  }
}

// ---------------------------------------------------------------------------
// Kernel 4: gather-aggregate, wave per node, lane = feature.
// BRANCHLESS lockstep over the node's S per-shard segments: all S index
// loads and all S row loads issue unconditionally every iteration (inactive
// streams use a clamped-safe index 0 -> L1 hit), accumulate predicated.
// Round-6 lesson: `if (p<q)` around the loads serialized them; this version
// gives the memory system S independent row-gathers per latency hop.
// ---------------------------------------------------------------------------
template <int S>
__global__ __launch_bounds__(256) void gin_gather_sharded(
    const float* __restrict__ x, const int* __restrict__ C,
    const int* __restrict__ sorted_src, float* __restrict__ agg,
    int n_nodes) {
  const int lane = threadIdx.x & 63;
  const int wave = (int)((blockIdx.x * blockDim.x + threadIdx.x) >> 6);
  if (wave >= n_nodes) return;

  int p[S], q[S];
  float acc[S];
  bool more = false;
#pragma unroll
  for (int s = 0; s < S; ++s) {
    const int k = s * n_nodes + wave;
    q[s] = C[k];
    p[s] = (k == 0) ? 0 : C[k - 1];
    acc[s] = 0.0f;
    more = more || (p[s] < q[s]);
  }

  while (more) {
    int act[S], srcs[S];
#pragma unroll
    for (int s = 0; s < S; ++s) {
      act[s] = (p[s] < q[s]) ? 1 : 0;
      srcs[s] = sorted_src[act[s] ? p[s] : 0];  // unconditional load
    }
    float rows[S];
#pragma unroll
    for (int s = 0; s < S; ++s) {
      rows[s] = x[(size_t)srcs[s] * D + lane];  // unconditional load
    }
    more = false;
#pragma unroll
    for (int s = 0; s < S; ++s) {
      acc[s] += act[s] ? rows[s] : 0.0f;
      p[s] += act[s];
      more = more || (p[s] < q[s]);
    }
  }

  float r = 0.0f;
#pragma unroll
  for (int s = 0; s < S; ++s) r += acc[s];
  agg[(size_t)wave * D + lane] = r;
}

// ---------------------------------------------------------------------------
// Fallback scatter (if ws too small): scalar float atomics, wave per edge.
// ---------------------------------------------------------------------------
__global__ __launch_bounds__(256) void gin_scatter_atomic(
    const float* __restrict__ x, const void* __restrict__ edge_index,
    float* __restrict__ agg, int n_edges) {
  DETECT_IS64(edge_index);
  const int* ei32 = (const int*)edge_index;
  const long long* ei64 = (const long long*)edge_index;
  const int lane = threadIdx.x & 63;
  int wave = (int)((blockIdx.x * blockDim.x + threadIdx.x) >> 6);
  const int nwaves = (int)((gridDim.x * blockDim.x) >> 6);
  for (int e = wave; e < n_edges; e += nwaves) {
    int src, dst;
    if (s_is64) {
      src = (int)ei64[e];
      dst = (int)ei64[n_edges + e];
    } else {
      src = ei32[e];
      dst = ei32[n_edges + e];
    }
    atomicAdd(&agg[(size_t)dst * D + lane], x[(size_t)src * D + lane]);
  }
}

// ---------------------------------------------------------------------------
// Fused per-node MLP, thread-per-node, NO LDS.
//   z = (1+eps)*x + agg ;  h = relu(W1 z + b1) ;  out = W2 h + b2
// Weight addresses depend only on compile-time loop indices -> the AMDGPU
// uniformity analysis scalarizes them (s_load_dwordx4 + SGPR-operand FMAs).
// Round-6 lesson: the LDS-broadcast version issued 2048 ds_read_b128 per
// thread (205M total) = LDS-pipe bound ~150us; FLOP floor is ~10us.
// Both layers fully unrolled so z[]/h[] stay statically indexed in VGPRs.
// agg_in may alias out (each thread reads only its own row before writing).
// ---------------------------------------------------------------------------
__global__ __launch_bounds__(256) void gin_mlp_kernel(
    const float* __restrict__ x,
    const float* __restrict__ agg_in,
    const float* __restrict__ eps_p,
    const float* __restrict__ W1, const float* __restrict__ b1,
    const float* __restrict__ W2, const float* __restrict__ b2,
    float* __restrict__ out,
    int n_nodes) {
  const int n = (int)(blockIdx.x * blockDim.x + threadIdx.x);
  if (n >= n_nodes) return;

  const float scale = 1.0f + eps_p[0];
  const float4* xr = (const float4*)(x + (size_t)n * D);
  const float4* ar = (const float4*)(agg_in + (size_t)n * D);
  const float4* W1v = (const float4*)W1;
  const float4* W2v = (const float4*)W2;

  float4 z[16];
#pragma unroll
  for (int q = 0; q < 16; ++q) {
    const float4 xv = xr[q];
    const float4 av = ar[q];
    z[q].x = scale * xv.x + av.x;
    z[q].y = scale * xv.y + av.y;
    z[q].z = scale * xv.z + av.z;
    z[q].w = scale * xv.w + av.w;
  }

  float h[64];
#pragma unroll
  for (int j = 0; j < 64; ++j) {
    float acc = b1[j];  // uniform -> s_load
#pragma unroll
    for (int q = 0; q < 16; ++q) {
      const float4 w = W1v[j * 16 + q];  // uniform -> s_load_dwordx4
      acc += w.x * z[q].x + w.y * z[q].y + w.z * z[q].z + w.w * z[q].w;
    }
    h[j] = fmaxf(acc, 0.0f);
  }

  float4* orow = (float4*)(out + (size_t)n * D);
#pragma unroll
  for (int j4 = 0; j4 < 16; ++j4) {
    float4 o;
#pragma unroll
    for (int c = 0; c < 4; ++c) {
      const int j = 4 * j4 + c;
      float acc = b2[j];  // uniform -> s_load
#pragma unroll
      for (int q = 0; q < 16; ++q) {
        const float4 w = W2v[j * 16 + q];  // uniform -> s_load_dwordx4
        acc += w.x * h[4 * q + 0] + w.y * h[4 * q + 1] +
               w.z * h[4 * q + 2] + w.w * h[4 * q + 3];
      }
      ((float*)&o)[c] = acc;
    }
    orow[j4] = o;
  }
}

extern "C" void kernel_launch(void* const* d_in, const int* in_sizes, int n_in,
                              void* d_out, int out_size, void* d_ws, size_t ws_size,
                              hipStream_t stream) {
  const float* x   = (const float*)d_in[0];
  const void*  ei  = d_in[1];
  const float* eps = (const float*)d_in[2];
  const float* W1  = (const float*)d_in[3];
  const float* b1  = (const float*)d_in[4];
  const float* W2  = (const float*)d_in[5];
  const float* b2  = (const float*)d_in[6];
  float* out = (float*)d_out;

  const int n_nodes = in_sizes[0] / D;
  const int n_edges = in_sizes[1] / 2;

  // Pick the largest shard count the workspace supports.
  // ws layout (ints): C[S*n_nodes] | tsum[SCAN_CHUNKS] | sorted[E]
  int S = 0;
  for (int cand = 8; cand >= 1; cand >>= 1) {
    const size_t need =
        ((size_t)cand * n_nodes + SCAN_CHUNKS + (size_t)n_edges) * 4;
    if (ws_size >= need) { S = cand; break; }
  }

  if (S > 0) {
    int* C      = (int*)d_ws;
    int* tsum   = C + (size_t)S * n_nodes;
    int* sorted = tsum + SCAN_CHUNKS;
    const int total = S * n_nodes;

    (void)hipMemsetAsync(C, 0, (size_t)total * 4, stream);

    gin_hist_sharded<<<EDGE_GRID, EDGE_BLOCK, 0, stream>>>(ei, C, n_edges,
                                                           n_nodes, S);

    const int chunk = (total + SCAN_CHUNKS - 1) / SCAN_CHUNKS;
    gin_scan_a<<<SCAN_CHUNKS / 256, 256, 0, stream>>>(C, tsum, total, chunk);
    gin_scan_b<<<1, 1024, 0, stream>>>(tsum);
    gin_scan_c<<<SCAN_CHUNKS / 256, 256, 0, stream>>>(C, tsum, total, chunk);

    gin_place_sharded<<<EDGE_GRID, EDGE_BLOCK, 0, stream>>>(ei, C, sorted,
                                                            n_edges, n_nodes,
                                                            S);

    const int gather_blocks = (n_nodes * 64 + 255) / 256;
    switch (S) {
      case 8:
        gin_gather_sharded<8><<<gather_blocks, 256, 0, stream>>>(
            x, C, sorted, out, n_nodes);
        break;
      case 4:
        gin_gather_sharded<4><<<gather_blocks, 256, 0, stream>>>(
            x, C, sorted, out, n_nodes);
        break;
      case 2:
        gin_gather_sharded<2><<<gather_blocks, 256, 0, stream>>>(
            x, C, sorted, out, n_nodes);
        break;
      default:
        gin_gather_sharded<1><<<gather_blocks, 256, 0, stream>>>(
            x, C, sorted, out, n_nodes);
        break;
    }
  } else {
    (void)hipMemsetAsync(out, 0, (size_t)n_nodes * D * sizeof(float), stream);
    gin_scatter_atomic<<<4096, 256, 0, stream>>>(x, ei, out, n_edges);
  }

  const int mlp_blocks = (n_nodes + 255) / 256;
  gin_mlp_kernel<<<mlp_blocks, 256, 0, stream>>>(x, out, eps, W1, b1, W2, b2,
                                                 out, n_nodes);
}

// Round 11
// 323.536 us; speedup vs baseline: 1.2258x; 1.2258x over previous
//
#include <hip/hip_runtime.h>

#define D 64

// ---------------------------------------------------------------------------
// edge_index dtype detection (int32 vs int64), done per-block on device.
// int64 little-endian with values < 2^32 => every odd uint32 word is 0.
// int32 random indices in [0,100000): P(64 odd words all zero) ~ 1e-320.
// ---------------------------------------------------------------------------
#define DETECT_IS64(ei)                                        \
  __shared__ int s_is64;                                       \
  if (threadIdx.x == 0) {                                      \
    const unsigned int* w_ = (const unsigned int*)(ei);        \
    int is64_ = 1;                                             \
    for (int i_ = 0; i_ < 64; ++i_) {                          \
      if (w_[2 * i_ + 1] != 0u) { is64_ = 0; break; }          \
    }                                                          \
    s_is64 = is64_;                                            \
  }                                                            \
  __syncthreads();

// Grid/block for hist & place MUST be identical: shard = blockIdx & (S-1)
// must map each edge to the same shard in both kernels.
#define EDGE_GRID 4096
#define EDGE_BLOCK 256

// Scan parallelism: 8192 chunks (round-5 lesson: 1024 x 782 serial iters
// was 335 us at 0.18% occupancy; 8192 x ~98 restores latency hiding).
#define SCAN_CHUNKS 8192

// ---------------------------------------------------------------------------
// Kernel 1: sharded histogram. key = shard*N + dst, shard = blockIdx&(S-1).
// ---------------------------------------------------------------------------
__global__ __launch_bounds__(256) void gin_hist_sharded(
    const void* __restrict__ edge_index, int* __restrict__ C,
    int n_edges, int n_nodes, int nshard) {
  DETECT_IS64(edge_index);
  const int* ei32 = (const int*)edge_index;
  const long long* ei64 = (const long long*)edge_index;
  int* Cs = C + (size_t)(blockIdx.x & (nshard - 1)) * n_nodes;
  const int i = (int)(blockIdx.x * blockDim.x + threadIdx.x);
  const int stride = (int)(gridDim.x * blockDim.x);
  for (int e = i; e < n_edges; e += stride) {
    const int dst = s_is64 ? (int)ei64[n_edges + e] : ei32[n_edges + e];
    atomicAdd(&Cs[dst], 1);
  }
}

// ---------------------------------------------------------------------------
// Kernels 2a/2b/2c: in-place exclusive scan of C[total], SCAN_CHUNKS chunks.
// ---------------------------------------------------------------------------
__global__ __launch_bounds__(256) void gin_scan_a(
    const int* __restrict__ C, int* __restrict__ tsum, int total, int chunk) {
  const int t = (int)(blockIdx.x * blockDim.x + threadIdx.x);
  if (t >= SCAN_CHUNKS) return;
  const int beg = t * chunk;
  const int end = min(beg + chunk, total);
  int s = 0;
  for (int i = beg; i < end; ++i) s += C[i];
  tsum[t] = s;
}

// One block, 1024 threads; each thread owns 8 contiguous partials.
__global__ __launch_bounds__(1024) void gin_scan_b(int* __restrict__ tsum) {
  __shared__ int ls[1024];
  const int t = threadIdx.x;
  int v[8];
  int s = 0;
#pragma unroll
  for (int i = 0; i < 8; ++i) {
    v[i] = tsum[t * 8 + i];
    s += v[i];
  }
  ls[t] = s;
  __syncthreads();
  for (int o = 1; o < 1024; o <<= 1) {
    const int a = (t >= o) ? ls[t - o] : 0;
    __syncthreads();
    ls[t] += a;
    __syncthreads();
  }
  int run = ls[t] - s;  // exclusive over this thread's 8
#pragma unroll
  for (int i = 0; i < 8; ++i) {
    tsum[t * 8 + i] = run;
    run += v[i];
  }
}

__global__ __launch_bounds__(256) void gin_scan_c(
    int* __restrict__ C, const int* __restrict__ tsum, int total, int chunk) {
  const int t = (int)(blockIdx.x * blockDim.x + threadIdx.x);
  if (t >= SCAN_CHUNKS) return;
  const int beg = t * chunk;
  const int end = min(beg + chunk, total);
  int run = tsum[t];
  for (int i = beg; i < end; ++i) {
    const int c = C[i];
    C[i] = run;
    run += c;
  }
}

// ---------------------------------------------------------------------------
// Kernel 3: sharded placement. pos = atomicAdd(&C[shard*N+dst], 1).
// After this kernel, C[k] = exclusive_prefix[k+1].
// ---------------------------------------------------------------------------
__global__ __launch_bounds__(256) void gin_place_sharded(
    const void* __restrict__ edge_index, int* __restrict__ C,
    int* __restrict__ sorted_src, int n_edges, int n_nodes, int nshard) {
  DETECT_IS64(edge_index);
  const int* ei32 = (const int*)edge_index;
  const long long* ei64 = (const long long*)edge_index;
  int* Cs = C + (size_t)(blockIdx.x & (nshard - 1)) * n_nodes;
  const int i = (int)(blockIdx.x * blockDim.x + threadIdx.x);
  const int stride = (int)(gridDim.x * blockDim.x);
  for (int e = i; e < n_edges; e += stride) {
    int src, dst;
    if (s_is64) {
      src = (int)ei64[e];
      dst = (int)ei64[n_edges + e];
    } else {
      src = ei32[e];
      dst = ei32[n_edges + e];
    }
    const int pos = atomicAdd(&Cs[dst], 1);
    sorted_src[pos] = src;
  }
}

// ---------------------------------------------------------------------------
// Kernel 4: gather-aggregate, wave per node, lane = feature. Branchless
// lockstep over the node's S per-shard segments (round-6 lesson).
// ---------------------------------------------------------------------------
template <int S>
__global__ __launch_bounds__(256) void gin_gather_sharded(
    const float* __restrict__ x, const int* __restrict__ C,
    const int* __restrict__ sorted_src, float* __restrict__ agg,
    int n_nodes) {
  const int lane = threadIdx.x & 63;
  const int wave = (int)((blockIdx.x * blockDim.x + threadIdx.x) >> 6);
  if (wave >= n_nodes) return;

  int p[S], q[S];
  float acc[S];
  bool more = false;
#pragma unroll
  for (int s = 0; s < S; ++s) {
    const int k = s * n_nodes + wave;
    q[s] = C[k];
    p[s] = (k == 0) ? 0 : C[k - 1];
    acc[s] = 0.0f;
    more = more || (p[s] < q[s]);
  }

  while (more) {
    int act[S], srcs[S];
#pragma unroll
    for (int s = 0; s < S; ++s) {
      act[s] = (p[s] < q[s]) ? 1 : 0;
      srcs[s] = sorted_src[act[s] ? p[s] : 0];  // unconditional load
    }
    float rows[S];
#pragma unroll
    for (int s = 0; s < S; ++s) {
      rows[s] = x[(size_t)srcs[s] * D + lane];  // unconditional load
    }
    more = false;
#pragma unroll
    for (int s = 0; s < S; ++s) {
      acc[s] += act[s] ? rows[s] : 0.0f;
      p[s] += act[s];
      more = more || (p[s] < q[s]);
    }
  }

  float r = 0.0f;
#pragma unroll
  for (int s = 0; s < S; ++s) r += acc[s];
  agg[(size_t)wave * D + lane] = r;
}

// ---------------------------------------------------------------------------
// Fallback scatter (if ws too small): scalar float atomics, wave per edge.
// ---------------------------------------------------------------------------
__global__ __launch_bounds__(256) void gin_scatter_atomic(
    const float* __restrict__ x, const void* __restrict__ edge_index,
    float* __restrict__ agg, int n_edges) {
  DETECT_IS64(edge_index);
  const int* ei32 = (const int*)edge_index;
  const long long* ei64 = (const long long*)edge_index;
  const int lane = threadIdx.x & 63;
  int wave = (int)((blockIdx.x * blockDim.x + threadIdx.x) >> 6);
  const int nwaves = (int)((gridDim.x * blockDim.x) >> 6);
  for (int e = wave; e < n_edges; e += nwaves) {
    int src, dst;
    if (s_is64) {
      src = (int)ei64[e];
      dst = (int)ei64[n_edges + e];
    } else {
      src = ei32[e];
      dst = ei32[n_edges + e];
    }
    atomicAdd(&agg[(size_t)dst * D + lane], x[(size_t)src * D + lane]);
  }
}

// ---------------------------------------------------------------------------
// Kernel 5: block-tiled MLP (vector f32 GEMM).
//   z = (1+eps)*x + agg ;  h = relu(W1 z + b1) ;  out = W2 h + b2
// Block = 256 threads = 128 nodes. Thread tile = 8 nodes x 4 outputs
// (32 f32 accumulators, statically indexed). Per k-quad: 12 ds_read_b128
// feed 128 FMAs. Round-10 lesson: thread-per-node had 1.5 waves/SIMD and
// s_load stalls (VALUBusy 14%); this gives 12 waves/CU and amortizes
// weight reads over 128 nodes.
// LDS geometry:
//  - zs[128][72]: node stride 72 words -> the 4 per-wave node addresses hit
//    bank groups {0,8,16,24} (conflict-free), 16B aligned (72%4==0).
//  - w1s/w2s[64][64] with kq-slot XOR swizzle slot=kq^((j>>2)&7): the 16 jg
//    lanes spread over 8 bank groups (2-way = free).
//  - h is written back into zs between the two layers (two barriers).
// agg_in aliases out: each block reads only its own 128 rows before
// overwriting them.
// ---------------------------------------------------------------------------
__global__ __launch_bounds__(256) void gin_mlp_tiled(
    const float* __restrict__ x,
    const float* __restrict__ agg_in,
    const float* __restrict__ eps_p,
    const float* __restrict__ W1, const float* __restrict__ b1,
    const float* __restrict__ W2, const float* __restrict__ b2,
    float* __restrict__ out,
    int n_nodes) {
  __shared__ float zs[128 * 72];   // z tile; reused for h
  __shared__ float w1s[64 * 64];
  __shared__ float w2s[64 * 64];

  const int t = (int)threadIdx.x;
  const int base = (int)blockIdx.x * 128;
  const float scale = 1.0f + eps_p[0];

  // --- stage weights (kq-slot swizzled) ---
  {
    const float4* W1v = (const float4*)W1;
    const float4* W2v = (const float4*)W2;
#pragma unroll
    for (int i = 0; i < 4; ++i) {
      const int idx = t + 256 * i;  // 0..1023
      const int j = idx >> 4;
      const int kq = idx & 15;
      const int slot = kq ^ ((j >> 2) & 7);
      *(float4*)&w1s[j * 64 + slot * 4] = W1v[idx];
      *(float4*)&w2s[j * 64 + slot * 4] = W2v[idx];
    }
  }

  // --- stage z = scale*x + agg (zero-fill out-of-range rows) ---
  {
#pragma unroll
    for (int i = 0; i < 8; ++i) {
      const int idx = t + 256 * i;  // 0..2047
      const int row = idx >> 4;
      const int kq = idx & 15;
      const int g = base + row;
      float4 zv;
      zv.x = 0.0f; zv.y = 0.0f; zv.z = 0.0f; zv.w = 0.0f;
      if (g < n_nodes) {
        const float4 xv = *(const float4*)(x + (size_t)g * D + kq * 4);
        const float4 av = *(const float4*)(agg_in + (size_t)g * D + kq * 4);
        zv.x = scale * xv.x + av.x;
        zv.y = scale * xv.y + av.y;
        zv.z = scale * xv.z + av.z;
        zv.w = scale * xv.w + av.w;
      }
      *(float4*)&zs[row * 72 + kq * 4] = zv;
    }
  }
  __syncthreads();

  const int jg = t & 15;  // output quad: j = 4*jg + c
  const int mg = t >> 4;  // node sub-index: node = r*16 + mg
  const float4 b1q = ((const float4*)b1)[jg];
  const float4 b2q = ((const float4*)b2)[jg];
  const int wswz = (jg & 7);  // == ((j>>2)&7) for j = 4*jg+c, c<4

  float acc[8][4];
#pragma unroll
  for (int r = 0; r < 8; ++r) {
    acc[r][0] = b1q.x; acc[r][1] = b1q.y;
    acc[r][2] = b1q.z; acc[r][3] = b1q.w;
  }

  // --- layer 1: acc += z . W1^T ---
#pragma unroll 4
  for (int kq = 0; kq < 16; ++kq) {
    float4 wq[4];
#pragma unroll
    for (int c = 0; c < 4; ++c) {
      wq[c] = *(const float4*)&w1s[(4 * jg + c) * 64 + ((kq ^ wswz) * 4)];
    }
#pragma unroll
    for (int r = 0; r < 8; ++r) {
      const float4 zq = *(const float4*)&zs[(r * 16 + mg) * 72 + kq * 4];
#pragma unroll
      for (int c = 0; c < 4; ++c) {
        acc[r][c] += zq.x * wq[c].x + zq.y * wq[c].y +
                     zq.z * wq[c].z + zq.w * wq[c].w;
      }
    }
  }

  // --- relu, write h back into zs ---
  __syncthreads();  // all zs reads done
#pragma unroll
  for (int r = 0; r < 8; ++r) {
    float4 hv;
    hv.x = fmaxf(acc[r][0], 0.0f);
    hv.y = fmaxf(acc[r][1], 0.0f);
    hv.z = fmaxf(acc[r][2], 0.0f);
    hv.w = fmaxf(acc[r][3], 0.0f);
    *(float4*)&zs[(r * 16 + mg) * 72 + jg * 4] = hv;
  }
  __syncthreads();

  // --- layer 2: acc = b2 + h . W2^T ---
#pragma unroll
  for (int r = 0; r < 8; ++r) {
    acc[r][0] = b2q.x; acc[r][1] = b2q.y;
    acc[r][2] = b2q.z; acc[r][3] = b2q.w;
  }
#pragma unroll 4
  for (int kq = 0; kq < 16; ++kq) {
    float4 wq[4];
#pragma unroll
    for (int c = 0; c < 4; ++c) {
      wq[c] = *(const float4*)&w2s[(4 * jg + c) * 64 + ((kq ^ wswz) * 4)];
    }
#pragma unroll
    for (int r = 0; r < 8; ++r) {
      const float4 zq = *(const float4*)&zs[(r * 16 + mg) * 72 + kq * 4];
#pragma unroll
      for (int c = 0; c < 4; ++c) {
        acc[r][c] += zq.x * wq[c].x + zq.y * wq[c].y +
                     zq.z * wq[c].z + zq.w * wq[c].w;
      }
    }
  }

  // --- store out tile ---
#pragma unroll
  for (int r = 0; r < 8; ++r) {
    const int g = base + r * 16 + mg;
    if (g < n_nodes) {
      float4 ov;
      ov.x = acc[r][0]; ov.y = acc[r][1];
      ov.z = acc[r][2]; ov.w = acc[r][3];
      *(float4*)(out + (size_t)g * D + jg * 4) = ov;
    }
  }
}

extern "C" void kernel_launch(void* const* d_in, const int* in_sizes, int n_in,
                              void* d_out, int out_size, void* d_ws, size_t ws_size,
                              hipStream_t stream) {
  const float* x   = (const float*)d_in[0];
  const void*  ei  = d_in[1];
  const float* eps = (const float*)d_in[2];
  const float* W1  = (const float*)d_in[3];
  const float* b1  = (const float*)d_in[4];
  const float* W2  = (const float*)d_in[5];
  const float* b2  = (const float*)d_in[6];
  float* out = (float*)d_out;

  const int n_nodes = in_sizes[0] / D;
  const int n_edges = in_sizes[1] / 2;

  // Pick the largest shard count the workspace supports.
  // ws layout (ints): C[S*n_nodes] | tsum[SCAN_CHUNKS] | sorted[E]
  int S = 0;
  for (int cand = 8; cand >= 1; cand >>= 1) {
    const size_t need =
        ((size_t)cand * n_nodes + SCAN_CHUNKS + (size_t)n_edges) * 4;
    if (ws_size >= need) { S = cand; break; }
  }

  if (S > 0) {
    int* C      = (int*)d_ws;
    int* tsum   = C + (size_t)S * n_nodes;
    int* sorted = tsum + SCAN_CHUNKS;
    const int total = S * n_nodes;

    (void)hipMemsetAsync(C, 0, (size_t)total * 4, stream);

    gin_hist_sharded<<<EDGE_GRID, EDGE_BLOCK, 0, stream>>>(ei, C, n_edges,
                                                           n_nodes, S);

    const int chunk = (total + SCAN_CHUNKS - 1) / SCAN_CHUNKS;
    gin_scan_a<<<SCAN_CHUNKS / 256, 256, 0, stream>>>(C, tsum, total, chunk);
    gin_scan_b<<<1, 1024, 0, stream>>>(tsum);
    gin_scan_c<<<SCAN_CHUNKS / 256, 256, 0, stream>>>(C, tsum, total, chunk);

    gin_place_sharded<<<EDGE_GRID, EDGE_BLOCK, 0, stream>>>(ei, C, sorted,
                                                            n_edges, n_nodes,
                                                            S);

    const int gather_blocks = (n_nodes * 64 + 255) / 256;
    switch (S) {
      case 8:
        gin_gather_sharded<8><<<gather_blocks, 256, 0, stream>>>(
            x, C, sorted, out, n_nodes);
        break;
      case 4:
        gin_gather_sharded<4><<<gather_blocks, 256, 0, stream>>>(
            x, C, sorted, out, n_nodes);
        break;
      case 2:
        gin_gather_sharded<2><<<gather_blocks, 256, 0, stream>>>(
            x, C, sorted, out, n_nodes);
        break;
      default:
        gin_gather_sharded<1><<<gather_blocks, 256, 0, stream>>>(
            x, C, sorted, out, n_nodes);
        break;
    }
  } else {
    (void)hipMemsetAsync(out, 0, (size_t)n_nodes * D * sizeof(float), stream);
    gin_scatter_atomic<<<4096, 256, 0, stream>>>(x, ei, out, n_edges);
  }

  const int mlp_blocks = (n_nodes + 127) / 128;
  gin_mlp_tiled<<<mlp_blocks, 256, 0, stream>>>(x, out, eps, W1, b1, W2, b2,
                                                out, n_nodes);
}